// Round 9
// baseline (698.110 us; speedup 1.0000x reference)
//
#include <hip/hip_runtime.h>
#include <hip/hip_fp16.h>
#include <cmath>

// SSIM fused kernel v9 = v6 structure + concurrency push (4 -> 5 blocks/CU):
// - LDS 37888 -> 28416 B: (mu1,mu2) plane packed as f16 half2 (RN! pkrtz/RTZ
//   would bias the final mean ~1e-3), ms/mx stay f32. 5 blocks/CU by LDS.
// - Liveness-ordered phase 1 (conv plane -> store -> next, in-place products)
//   + __launch_bounds__(256,5) to cap VGPR at 102 (5 waves/SIMD). Natural
//   liveness ~60-70 so no spills expected (watch WRITE_SIZE).
// - rcp division, no setprio, parallel 2-stage tail reduction.

#define W 512
#define H 512
#define OWD 502
#define OHD 502
#define TILEC 32
#define TILER 64
#define INR 74            // logical halo'd rows; phys: 37 even + 37 odd
#define ESPLIT 37         // phys offset of odd rows
#define NVALID 12096192   // 48 * 502 * 502
#define NBLKX 16
#define NBLKY 8
#define NPART (NBLKX * NBLKY * 48 * 4)   // 24576 = one partial per wave
#define NRB 24                            // reduce1 blocks (24*1024 = NPART)

struct Weights { float g[11]; };

__global__ __launch_bounds__(256, 5) void ssim_kernel(
    const float* __restrict__ x, const float* __restrict__ y,
    float* __restrict__ partial, float* __restrict__ accum, int use_atomic, Weights wt)
{
    __shared__ __align__(16) __half2 hmu[INR][TILEC];  // (mu1, mu2)  9472 B
    __shared__ __align__(16) float   hms[INR][TILEC];  // conv(x^2+y^2) 9472 B
    __shared__ __align__(16) float   hmx[INR][TILEC];  // conv(x*y)     9472 B

    const int tid = threadIdx.x;
    const int r0 = blockIdx.y * TILER;
    const int c0 = blockIdx.x * TILEC;
    const size_t plane = (size_t)blockIdx.z * (W * H);
    const float* xp = x + plane;
    const float* yp = y + plane;

    // ---- Phase 1: horizontal pass over 74 physical rows x 8 col-groups.
    // phys p < 37 -> logical row 2p (even); p >= 37 -> logical 2(p-37)+1 (odd).
    for (int i = tid; i < INR * 8; i += 256) {
        const int p = i >> 3;                 // physical row 0..73
        const int cg = (i & 7) << 2;          // col group offset 0..28
        const int lr = (p < ESPLIT) ? (2 * p) : (2 * (p - ESPLIT) + 1);
        const int gr = r0 + lr;
        float xv[16], yv[16];
        if (gr < H) {
            const float* xr = xp + (size_t)gr * W;
            const float* yr = yp + (size_t)gr * W;
            #pragma unroll
            for (int q = 0; q < 4; q++) {
                const int gc = c0 + cg + 4 * q;
                float4 a = make_float4(0.f, 0.f, 0.f, 0.f);
                float4 b = make_float4(0.f, 0.f, 0.f, 0.f);
                if (gc < W) {  // W%4==0, gc%4==0 -> float4 fully in or out
                    a = *(const float4*)(xr + gc);
                    b = *(const float4*)(yr + gc);
                }
                xv[4*q+0] = a.x; xv[4*q+1] = a.y; xv[4*q+2] = a.z; xv[4*q+3] = a.w;
                yv[4*q+0] = b.x; yv[4*q+1] = b.y; yv[4*q+2] = b.z; yv[4*q+3] = b.w;
            }
        } else {
            #pragma unroll
            for (int j = 0; j < 16; j++) { xv[j] = 0.f; yv[j] = 0.f; }
        }

        // conv mu1, mu2 -> pack f16 (RN) -> store immediately (kills m1/m2)
        {
            float m1[4] = {0.f,0.f,0.f,0.f}, m2[4] = {0.f,0.f,0.f,0.f};
            #pragma unroll
            for (int k = 0; k < 11; k++) {
                const float w = wt.g[k];
                #pragma unroll
                for (int j = 0; j < 4; j++) {
                    m1[j] += w * xv[j + k];
                    m2[j] += w * yv[j + k];
                }
            }
            __half2 hm[4];
            #pragma unroll
            for (int j = 0; j < 4; j++)
                hm[j] = __halves2half2(__float2half(m1[j]), __float2half(m2[j]));
            *(float4*)&hmu[p][cg] = *(const float4*)hm;
        }
        // conv xy -> store (t reuses no extra arrays beyond 16)
        {
            float t[16];
            #pragma unroll
            for (int j = 0; j < 16; j++) t[j] = xv[j] * yv[j];
            float mx[4] = {0.f,0.f,0.f,0.f};
            #pragma unroll
            for (int k = 0; k < 11; k++) {
                const float w = wt.g[k];
                #pragma unroll
                for (int j = 0; j < 4; j++) mx[j] += w * t[j + k];
            }
            *(float4*)&hmx[p][cg] = make_float4(mx[0], mx[1], mx[2], mx[3]);
        }
        // conv (x^2 + y^2) in place (xv <- xv^2 + yv^2) -> store
        {
            #pragma unroll
            for (int j = 0; j < 16; j++) {
                yv[j] = yv[j] * yv[j];
                xv[j] = fmaf(xv[j], xv[j], yv[j]);
            }
            float ms[4] = {0.f,0.f,0.f,0.f};
            #pragma unroll
            for (int k = 0; k < 11; k++) {
                const float w = wt.g[k];
                #pragma unroll
                for (int j = 0; j < 4; j++) ms[j] += w * xv[j + k];
            }
            *(float4*)&hms[p][cg] = make_float4(ms[0], ms[1], ms[2], ms[3]);
        }
    }
    __syncthreads();

    // ---- Phase 2: vertical pass + SSIM. All 256 threads: 2 rows x 4 cols.
    float lsum = 0.f;
    {
        const int rp = tid >> 3;         // row pair 0..31 -> rows 2rp, 2rp+1
        const int cg = (tid & 7) << 2;   // col group
        float a[4][2][4];                // mu1, mu2, ms, mx
        #pragma unroll
        for (int j = 0; j < 4; j++)
            #pragma unroll
            for (int rr = 0; rr < 2; rr++)
                #pragma unroll
                for (int e = 0; e < 4; e++) a[j][rr][e] = 0.f;

        #pragma unroll
        for (int t = 0; t < 12; t++) {
            // logical row 2rp+t -> phys: even at rp+t/2, odd at ESPLIT+rp+(t-1)/2
            const int prow = ((t & 1) == 0) ? (rp + (t >> 1))
                                            : (ESPLIT + rp + (t >> 1));
            float4 vmu = *(const float4*)&hmu[prow][cg];
            float4 vms = *(const float4*)&hms[prow][cg];
            float4 vmx = *(const float4*)&hmx[prow][cg];
            const __half2* hm = (const __half2*)&vmu;
            float v[4][4];
            #pragma unroll
            for (int j = 0; j < 4; j++) {
                const float2 f = __half22float2(hm[j]);
                v[0][j] = f.x; v[1][j] = f.y;
            }
            v[2][0] = vms.x; v[2][1] = vms.y; v[2][2] = vms.z; v[2][3] = vms.w;
            v[3][0] = vmx.x; v[3][1] = vmx.y; v[3][2] = vmx.z; v[3][3] = vmx.w;

            if (t <= 10) {   // tap for output row 0 (compile-time)
                const float w = wt.g[t];
                #pragma unroll
                for (int j = 0; j < 4; j++)
                    #pragma unroll
                    for (int e = 0; e < 4; e++) a[j][0][e] += w * v[j][e];
            }
            if (t >= 1) {    // tap for output row 1 (compile-time)
                const float w = wt.g[t - 1];
                #pragma unroll
                for (int j = 0; j < 4; j++)
                    #pragma unroll
                    for (int e = 0; e < 4; e++) a[j][1][e] += w * v[j][e];
            }
        }

        const float C1 = 1e-4f;   // (0.01*1)^2
        const float C2 = 9e-4f;   // (0.03*1)^2
        #pragma unroll
        for (int rr = 0; rr < 2; rr++) {
            const int orow = r0 + 2 * rp + rr;
            if (orow < OHD) {
                #pragma unroll
                for (int e = 0; e < 4; e++) {
                    const int ocol = c0 + cg + e;
                    if (ocol < OWD) {
                        const float mu1 = a[0][rr][e], mu2 = a[1][rr][e];
                        const float mu12 = mu1 * mu2;
                        const float mu1s = mu1 * mu1;
                        const float mu2s = mu2 * mu2;
                        const float sss = a[2][rr][e] - mu1s - mu2s;  // s11+s22
                        const float s12 = a[3][rr][e] - mu12;
                        const float num = (2.f * mu12 + C1) * (2.f * s12 + C2);
                        const float den = (mu1s + mu2s + C1) * (sss + C2);
                        lsum += num * __builtin_amdgcn_rcpf(den);
                    }
                }
            }
        }
    }

    // ---- Per-wave reduction; one partial (or atomic) per wave.
    #pragma unroll
    for (int off = 32; off > 0; off >>= 1) lsum += __shfl_down(lsum, off, 64);
    if ((tid & 63) == 0) {
        const int wave = tid >> 6;
        const int bid = (blockIdx.z * NBLKY + blockIdx.y) * NBLKX + blockIdx.x;
        if (use_atomic) unsafeAtomicAdd(accum, lsum);
        else partial[bid * 4 + wave] = lsum;
    }
}

// Stage-1 reduce: 24 blocks x 1024 threads, each block sums a 1024-chunk.
__global__ __launch_bounds__(1024) void reduce1_kernel(
    const float* __restrict__ partial, float* __restrict__ bsum)
{
    __shared__ float ws[16];
    float s = partial[blockIdx.x * 1024 + threadIdx.x];
    #pragma unroll
    for (int off = 32; off > 0; off >>= 1) s += __shfl_down(s, off, 64);
    const int wave = threadIdx.x >> 6;
    if ((threadIdx.x & 63) == 0) ws[wave] = s;
    __syncthreads();
    if (threadIdx.x == 0) {
        float t = 0.f;
        #pragma unroll
        for (int i = 0; i < 16; i++) t += ws[i];
        bsum[blockIdx.x] = t;
    }
}

// Stage-2 reduce: one wave sums the 24 block sums and divides.
__global__ void reduce2_kernel(const float* __restrict__ bsum, float* __restrict__ out)
{
    float s = (threadIdx.x < NRB) ? bsum[threadIdx.x] : 0.f;
    #pragma unroll
    for (int off = 32; off > 0; off >>= 1) s += __shfl_down(s, off, 64);
    if (threadIdx.x == 0) out[0] = s * (1.0f / (float)NVALID);
}

__global__ void finalize_kernel(const float* __restrict__ accum, float* __restrict__ out) {
    out[0] = accum[0] * (1.0f / (float)NVALID);
}

extern "C" void kernel_launch(void* const* d_in, const int* in_sizes, int n_in,
                              void* d_out, int out_size, void* d_ws, size_t ws_size,
                              hipStream_t stream) {
    const float* x = (const float*)d_in[0];
    const float* y = (const float*)d_in[1];
    float* out = (float*)d_out;
    float* ws = (float*)d_ws;

    // Gaussian window, computed in double like the numpy reference, cast to f32.
    Weights wt;
    {
        double g[11], s = 0.0;
        for (int i = 0; i < 11; i++) {
            double d = (double)(i - 5);
            g[i] = exp(-(d * d) / (2.0 * 1.5 * 1.5));
            s += g[i];
        }
        for (int i = 0; i < 11; i++) wt.g[i] = (float)(g[i] / s);
    }

    dim3 grid(NBLKX, NBLKY, 48);
    const size_t need = (size_t)(NPART + NRB) * sizeof(float);
    const int use_atomic = (ws_size < need) ? 1 : 0;
    if (use_atomic) {
        hipMemsetAsync(ws, 0, sizeof(float), stream);
        ssim_kernel<<<grid, 256, 0, stream>>>(x, y, ws, ws, 1, wt);
        finalize_kernel<<<1, 1, 0, stream>>>(ws, out);
    } else {
        float* bsum = ws + NPART;
        ssim_kernel<<<grid, 256, 0, stream>>>(x, y, ws, ws, 0, wt);
        reduce1_kernel<<<NRB, 1024, 0, stream>>>(ws, bsum);
        reduce2_kernel<<<1, 64, 0, stream>>>(bsum, out);
    }
}

// Round 11
// 114.012 us; speedup vs baseline: 6.1231x; 6.1231x over previous
//
#include <hip/hip_runtime.h>
#include <hip/hip_fp16.h>
#include <cmath>

// SSIM fused kernel v11 = v6 geometry + f16-packed MU plane only.
// - hA = (mu1,mu2) as __half2 (f16 safe for mu: enters products, no
//   cancellation; v9 passed with this). ms/mx MUST stay f32: sigma =
//   ms - mu^2 is catastrophic cancellation (v10 failed at 4.3e-4).
// - LDS 28416 B (was 37888): hA 9472 + hms 9472 + hmx 9472.
// - Phase-2: 36 ds_read_b128/thread (was 48), f32 accumulation.
// - No launch_bounds 2nd arg (caps VGPR wrongly -> spills; burned twice).

#define W 512
#define H 512
#define OWD 502
#define OHD 502
#define TILEC 32
#define TILER 64
#define INR 74            // logical halo'd rows; phys: 37 even + 37 odd
#define ESPLIT 37         // phys offset of odd rows
#define NVALID 12096192   // 48 * 502 * 502
#define NBLKX 16
#define NBLKY 8
#define NPART (NBLKX * NBLKY * 48 * 4)   // 24576 = one partial per wave
#define NRB 24                            // reduce1 blocks (24*1024 = NPART)

struct Weights { float g[11]; };
struct H2x4 { __half2 h[4]; };

__global__ __launch_bounds__(256) void ssim_kernel(
    const float* __restrict__ x, const float* __restrict__ y,
    float* __restrict__ partial, float* __restrict__ accum, int use_atomic, Weights wt)
{
    __shared__ __align__(16) __half2 hA[INR][TILEC];   // (mu1, mu2)    9472 B
    __shared__ __align__(16) float   hms[INR][TILEC];  // conv(x^2+y^2) 9472 B
    __shared__ __align__(16) float   hmx[INR][TILEC];  // conv(x*y)     9472 B

    const int tid = threadIdx.x;
    const int r0 = blockIdx.y * TILER;
    const int c0 = blockIdx.x * TILEC;
    const size_t plane = (size_t)blockIdx.z * (W * H);
    const float* xp = x + plane;
    const float* yp = y + plane;

    // ---- Phase 1: horizontal pass over 74 physical rows x 8 col-groups.
    // phys p < 37 -> logical row 2p (even); p >= 37 -> logical 2(p-37)+1 (odd).
    for (int i = tid; i < INR * 8; i += 256) {
        const int p = i >> 3;                 // physical row 0..73
        const int cg = (i & 7) << 2;          // col group offset 0..28
        const int lr = (p < ESPLIT) ? (2 * p) : (2 * (p - ESPLIT) + 1);
        const int gr = r0 + lr;
        float xv[16], yv[16];
        if (gr < H) {
            const float* xr = xp + (size_t)gr * W;
            const float* yr = yp + (size_t)gr * W;
            #pragma unroll
            for (int q = 0; q < 4; q++) {
                const int gc = c0 + cg + 4 * q;
                float4 a = make_float4(0.f, 0.f, 0.f, 0.f);
                float4 b = make_float4(0.f, 0.f, 0.f, 0.f);
                if (gc < W) {  // W%4==0, gc%4==0 -> float4 fully in or out
                    a = *(const float4*)(xr + gc);
                    b = *(const float4*)(yr + gc);
                }
                xv[4*q+0] = a.x; xv[4*q+1] = a.y; xv[4*q+2] = a.z; xv[4*q+3] = a.w;
                yv[4*q+0] = b.x; yv[4*q+1] = b.y; yv[4*q+2] = b.z; yv[4*q+3] = b.w;
            }
        } else {
            #pragma unroll
            for (int j = 0; j < 16; j++) { xv[j] = 0.f; yv[j] = 0.f; }
        }

        // mu1, mu2 (f32 conv) -> pack RN f16 -> store hA.
        {
            float m1[4] = {0.f,0.f,0.f,0.f}, m2[4] = {0.f,0.f,0.f,0.f};
            #pragma unroll
            for (int k = 0; k < 11; k++) {
                const float w = wt.g[k];
                #pragma unroll
                for (int j = 0; j < 4; j++) {
                    m1[j] += w * xv[j + k];
                    m2[j] += w * yv[j + k];
                }
            }
            H2x4 st;
            #pragma unroll
            for (int j = 0; j < 4; j++)
                st.h[j] = __halves2half2(__float2half(m1[j]), __float2half(m2[j]));
            *(H2x4*)&hA[p][cg] = st;
        }
        // xy conv -> f32 store; then ss conv in place -> f32 store.
        {
            float t[16];
            #pragma unroll
            for (int j = 0; j < 16; j++) t[j] = xv[j] * yv[j];
            float mx[4] = {0.f,0.f,0.f,0.f};
            #pragma unroll
            for (int k = 0; k < 11; k++) {
                const float w = wt.g[k];
                #pragma unroll
                for (int j = 0; j < 4; j++) mx[j] += w * t[j + k];
            }
            *(float4*)&hmx[p][cg] = make_float4(mx[0], mx[1], mx[2], mx[3]);

            #pragma unroll
            for (int j = 0; j < 16; j++) {
                yv[j] = yv[j] * yv[j];
                xv[j] = fmaf(xv[j], xv[j], yv[j]);   // x^2 + y^2
            }
            float ms[4] = {0.f,0.f,0.f,0.f};
            #pragma unroll
            for (int k = 0; k < 11; k++) {
                const float w = wt.g[k];
                #pragma unroll
                for (int j = 0; j < 4; j++) ms[j] += w * xv[j + k];
            }
            *(float4*)&hms[p][cg] = make_float4(ms[0], ms[1], ms[2], ms[3]);
        }
    }
    __syncthreads();

    // ---- Phase 2: vertical pass + SSIM. All 256 threads: 2 rows x 4 cols.
    float lsum = 0.f;
    {
        const int rp = tid >> 3;         // row pair 0..31 -> rows 2rp, 2rp+1
        const int cg = (tid & 7) << 2;   // col group
        float aM1[2][4], aM2[2][4], aS[2][4], aX[2][4];
        #pragma unroll
        for (int rr = 0; rr < 2; rr++)
            #pragma unroll
            for (int e = 0; e < 4; e++) {
                aM1[rr][e] = 0.f; aM2[rr][e] = 0.f;
                aS[rr][e] = 0.f;  aX[rr][e] = 0.f;
            }

        #pragma unroll
        for (int t = 0; t < 12; t++) {
            // logical row 2rp+t -> phys: even at rp+t/2, odd at ESPLIT+rp+(t-1)/2
            const int prow = ((t & 1) == 0) ? (rp + (t >> 1))
                                            : (ESPLIT + rp + (t >> 1));
            const H2x4 va = *(const H2x4*)&hA[prow][cg];
            const float4 vs = *(const float4*)&hms[prow][cg];
            const float4 vx = *(const float4*)&hmx[prow][cg];
            float m1v[4], m2v[4];
            #pragma unroll
            for (int j = 0; j < 4; j++) {
                const float2 f = __half22float2(va.h[j]);
                m1v[j] = f.x; m2v[j] = f.y;
            }
            const float sv[4] = {vs.x, vs.y, vs.z, vs.w};
            const float xvv[4] = {vx.x, vx.y, vx.z, vx.w};

            if (t <= 10) {   // tap for output row 0 (compile-time)
                const float w = wt.g[t];
                #pragma unroll
                for (int e = 0; e < 4; e++) {
                    aM1[0][e] += w * m1v[e];
                    aM2[0][e] += w * m2v[e];
                    aS[0][e]  += w * sv[e];
                    aX[0][e]  += w * xvv[e];
                }
            }
            if (t >= 1) {    // tap for output row 1 (compile-time)
                const float w = wt.g[t - 1];
                #pragma unroll
                for (int e = 0; e < 4; e++) {
                    aM1[1][e] += w * m1v[e];
                    aM2[1][e] += w * m2v[e];
                    aS[1][e]  += w * sv[e];
                    aX[1][e]  += w * xvv[e];
                }
            }
        }

        const float C1 = 1e-4f;   // (0.01*1)^2
        const float C2 = 9e-4f;   // (0.03*1)^2
        #pragma unroll
        for (int rr = 0; rr < 2; rr++) {
            const int orow = r0 + 2 * rp + rr;
            if (orow < OHD) {
                #pragma unroll
                for (int e = 0; e < 4; e++) {
                    const int ocol = c0 + cg + e;
                    if (ocol < OWD) {
                        const float mu1 = aM1[rr][e], mu2 = aM2[rr][e];
                        const float mu12 = mu1 * mu2;
                        const float mu1s = mu1 * mu1;
                        const float mu2s = mu2 * mu2;
                        const float sss = aS[rr][e] - mu1s - mu2s;  // s11+s22
                        const float s12 = aX[rr][e] - mu12;
                        const float num = (2.f * mu12 + C1) * (2.f * s12 + C2);
                        const float den = (mu1s + mu2s + C1) * (sss + C2);
                        lsum += num * __builtin_amdgcn_rcpf(den);
                    }
                }
            }
        }
    }

    // ---- Per-wave reduction; one partial (or atomic) per wave.
    #pragma unroll
    for (int off = 32; off > 0; off >>= 1) lsum += __shfl_down(lsum, off, 64);
    if ((tid & 63) == 0) {
        const int wave = tid >> 6;
        const int bid = (blockIdx.z * NBLKY + blockIdx.y) * NBLKX + blockIdx.x;
        if (use_atomic) unsafeAtomicAdd(accum, lsum);
        else partial[bid * 4 + wave] = lsum;
    }
}

// Stage-1 reduce: 24 blocks x 1024 threads, each block sums a 1024-chunk.
__global__ __launch_bounds__(1024) void reduce1_kernel(
    const float* __restrict__ partial, float* __restrict__ bsum)
{
    __shared__ float ws[16];
    float s = partial[blockIdx.x * 1024 + threadIdx.x];
    #pragma unroll
    for (int off = 32; off > 0; off >>= 1) s += __shfl_down(s, off, 64);
    const int wave = threadIdx.x >> 6;
    if ((threadIdx.x & 63) == 0) ws[wave] = s;
    __syncthreads();
    if (threadIdx.x == 0) {
        float t = 0.f;
        #pragma unroll
        for (int i = 0; i < 16; i++) t += ws[i];
        bsum[blockIdx.x] = t;
    }
}

// Stage-2 reduce: one wave sums the 24 block sums and divides.
__global__ void reduce2_kernel(const float* __restrict__ bsum, float* __restrict__ out)
{
    float s = (threadIdx.x < NRB) ? bsum[threadIdx.x] : 0.f;
    #pragma unroll
    for (int off = 32; off > 0; off >>= 1) s += __shfl_down(s, off, 64);
    if (threadIdx.x == 0) out[0] = s * (1.0f / (float)NVALID);
}

__global__ void finalize_kernel(const float* __restrict__ accum, float* __restrict__ out) {
    out[0] = accum[0] * (1.0f / (float)NVALID);
}

extern "C" void kernel_launch(void* const* d_in, const int* in_sizes, int n_in,
                              void* d_out, int out_size, void* d_ws, size_t ws_size,
                              hipStream_t stream) {
    const float* x = (const float*)d_in[0];
    const float* y = (const float*)d_in[1];
    float* out = (float*)d_out;
    float* ws = (float*)d_ws;

    // Gaussian window, computed in double like the numpy reference, cast to f32.
    Weights wt;
    {
        double g[11], s = 0.0;
        for (int i = 0; i < 11; i++) {
            double d = (double)(i - 5);
            g[i] = exp(-(d * d) / (2.0 * 1.5 * 1.5));
            s += g[i];
        }
        for (int i = 0; i < 11; i++) wt.g[i] = (float)(g[i] / s);
    }

    dim3 grid(NBLKX, NBLKY, 48);
    const size_t need = (size_t)(NPART + NRB) * sizeof(float);
    const int use_atomic = (ws_size < need) ? 1 : 0;
    if (use_atomic) {
        hipMemsetAsync(ws, 0, sizeof(float), stream);
        ssim_kernel<<<grid, 256, 0, stream>>>(x, y, ws, ws, 1, wt);
        finalize_kernel<<<1, 1, 0, stream>>>(ws, out);
    } else {
        float* bsum = ws + NPART;
        ssim_kernel<<<grid, 256, 0, stream>>>(x, y, ws, ws, 0, wt);
        reduce1_kernel<<<NRB, 1024, 0, stream>>>(ws, bsum);
        reduce2_kernel<<<1, 64, 0, stream>>>(bsum, out);
    }
}

// Round 12
// 82.674 us; speedup vs baseline: 8.4441x; 1.3791x over previous
//
#include <hip/hip_runtime.h>
#include <cmath>

// SSIM fused kernel v12 = v6 EXACTLY (best measured: 88.7 us) plus only:
//  1. parallel 2-stage tail reduction (was single-block serial reduce),
//  2. rcpf for the SSIM division (1-ulp, threshold 1.1e-4).
// v7-v11 lesson: five structural "improvements" all regressed; v6's simple
// 6144-block 2-phase structure with natural phase diversity is the local
// optimum. No launch_bounds 2nd arg (caps VGPR wrongly -> spills).

#define W 512
#define H 512
#define OWD 502
#define OHD 502
#define TILEC 32
#define TILER 64
#define INR 74            // logical halo'd rows; phys: 37 even + 37 odd
#define ESPLIT 37         // phys offset of odd rows
#define NVALID 12096192   // 48 * 502 * 502
#define NBLKX 16
#define NBLKY 8
#define NPART (NBLKX * NBLKY * 48 * 4)   // 24576 = one partial per wave
#define NRB 24                            // reduce1 blocks (24*1024 = NPART)

struct Weights { float g[11]; };

__global__ __launch_bounds__(256) void ssim_kernel(
    const float* __restrict__ x, const float* __restrict__ y,
    float* __restrict__ partial, float* __restrict__ accum, int use_atomic, Weights wt)
{
    __shared__ __align__(16) float hb[4][INR][TILEC];

    const int tid = threadIdx.x;
    const int r0 = blockIdx.y * TILER;
    const int c0 = blockIdx.x * TILEC;
    const size_t plane = (size_t)blockIdx.z * (W * H);
    const float* xp = x + plane;
    const float* yp = y + plane;

    // ---- Phase 1: horizontal pass over 74 physical rows x 8 col-groups.
    // phys p < 37 -> logical row 2p (even); p >= 37 -> logical 2(p-37)+1 (odd).
    for (int i = tid; i < INR * 8; i += 256) {
        const int p = i >> 3;                 // physical row 0..73
        const int cg = (i & 7) << 2;          // col group offset 0..28
        const int lr = (p < ESPLIT) ? (2 * p) : (2 * (p - ESPLIT) + 1);
        const int gr = r0 + lr;
        float xv[16], yv[16];
        if (gr < H) {
            const float* xr = xp + (size_t)gr * W;
            const float* yr = yp + (size_t)gr * W;
            #pragma unroll
            for (int q = 0; q < 4; q++) {
                const int gc = c0 + cg + 4 * q;
                float4 a = make_float4(0.f, 0.f, 0.f, 0.f);
                float4 b = make_float4(0.f, 0.f, 0.f, 0.f);
                if (gc < W) {  // W%4==0, gc%4==0 -> float4 fully in or out
                    a = *(const float4*)(xr + gc);
                    b = *(const float4*)(yr + gc);
                }
                xv[4*q+0] = a.x; xv[4*q+1] = a.y; xv[4*q+2] = a.z; xv[4*q+3] = a.w;
                yv[4*q+0] = b.x; yv[4*q+1] = b.y; yv[4*q+2] = b.z; yv[4*q+3] = b.w;
            }
        } else {
            #pragma unroll
            for (int j = 0; j < 16; j++) { xv[j] = 0.f; yv[j] = 0.f; }
        }
        // Hoisted products: ss = x^2 + y^2 (one plane), xy.
        float ssv[16], xyv[16];
        #pragma unroll
        for (int j = 0; j < 16; j++) {
            ssv[j] = xv[j] * xv[j] + yv[j] * yv[j];
            xyv[j] = xv[j] * yv[j];
        }
        float m1[4]  = {0.f, 0.f, 0.f, 0.f};
        float m2[4]  = {0.f, 0.f, 0.f, 0.f};
        float ms[4]  = {0.f, 0.f, 0.f, 0.f};
        float mx[4]  = {0.f, 0.f, 0.f, 0.f};
        #pragma unroll
        for (int k2 = 0; k2 < 11; k2++) {
            const float w = wt.g[k2];
            #pragma unroll
            for (int j = 0; j < 4; j++) {
                m1[j] += w * xv[j + k2];
                m2[j] += w * yv[j + k2];
                ms[j] += w * ssv[j + k2];
                mx[j] += w * xyv[j + k2];
            }
        }
        *(float4*)&hb[0][p][cg] = make_float4(m1[0], m1[1], m1[2], m1[3]);
        *(float4*)&hb[1][p][cg] = make_float4(m2[0], m2[1], m2[2], m2[3]);
        *(float4*)&hb[2][p][cg] = make_float4(ms[0], ms[1], ms[2], ms[3]);
        *(float4*)&hb[3][p][cg] = make_float4(mx[0], mx[1], mx[2], mx[3]);
    }
    __syncthreads();

    // ---- Phase 2: vertical pass + SSIM. All 256 threads: 2 rows x 4 cols.
    float lsum = 0.f;
    {
        const int rp = tid >> 3;         // row pair 0..31 -> rows 2rp, 2rp+1
        const int cg = (tid & 7) << 2;   // col group
        float a[4][2][4];
        #pragma unroll
        for (int j = 0; j < 4; j++)
            #pragma unroll
            for (int rr = 0; rr < 2; rr++)
                #pragma unroll
                for (int e = 0; e < 4; e++) a[j][rr][e] = 0.f;

        #pragma unroll
        for (int t = 0; t < 12; t++) {
            // logical row 2rp+t -> phys: even at rp+t/2, odd at ESPLIT+rp+(t-1)/2
            const int prow = ((t & 1) == 0) ? (rp + (t >> 1))
                                            : (ESPLIT + rp + (t >> 1));
            float4 v[4];
            #pragma unroll
            for (int j = 0; j < 4; j++) v[j] = *(const float4*)&hb[j][prow][cg];
            if (t <= 10) {   // tap for output row 0 (compile-time)
                const float w = wt.g[t];
                #pragma unroll
                for (int j = 0; j < 4; j++) {
                    a[j][0][0] += w * v[j].x; a[j][0][1] += w * v[j].y;
                    a[j][0][2] += w * v[j].z; a[j][0][3] += w * v[j].w;
                }
            }
            if (t >= 1) {    // tap for output row 1 (compile-time)
                const float w = wt.g[t - 1];
                #pragma unroll
                for (int j = 0; j < 4; j++) {
                    a[j][1][0] += w * v[j].x; a[j][1][1] += w * v[j].y;
                    a[j][1][2] += w * v[j].z; a[j][1][3] += w * v[j].w;
                }
            }
        }

        const float C1 = 1e-4f;   // (0.01*1)^2
        const float C2 = 9e-4f;   // (0.03*1)^2
        #pragma unroll
        for (int rr = 0; rr < 2; rr++) {
            const int orow = r0 + 2 * rp + rr;
            if (orow < OHD) {
                #pragma unroll
                for (int e = 0; e < 4; e++) {
                    const int ocol = c0 + cg + e;
                    if (ocol < OWD) {
                        const float mu1 = a[0][rr][e], mu2 = a[1][rr][e];
                        const float mu12 = mu1 * mu2;
                        const float mu1s = mu1 * mu1;
                        const float mu2s = mu2 * mu2;
                        const float sss = a[2][rr][e] - mu1s - mu2s;  // s11+s22
                        const float s12 = a[3][rr][e] - mu12;
                        const float num = (2.f * mu12 + C1) * (2.f * s12 + C2);
                        const float den = (mu1s + mu2s + C1) * (sss + C2);
                        lsum += num * __builtin_amdgcn_rcpf(den);
                    }
                }
            }
        }
    }

    // ---- Per-wave reduction; one partial (or atomic) per wave.
    #pragma unroll
    for (int off = 32; off > 0; off >>= 1) lsum += __shfl_down(lsum, off, 64);
    if ((tid & 63) == 0) {
        const int wave = tid >> 6;
        const int bid = (blockIdx.z * NBLKY + blockIdx.y) * NBLKX + blockIdx.x;
        if (use_atomic) unsafeAtomicAdd(accum, lsum);
        else partial[bid * 4 + wave] = lsum;
    }
}

// Stage-1 reduce: 24 blocks x 1024 threads, each block sums a 1024-chunk.
__global__ __launch_bounds__(1024) void reduce1_kernel(
    const float* __restrict__ partial, float* __restrict__ bsum)
{
    __shared__ float ws[16];
    float s = partial[blockIdx.x * 1024 + threadIdx.x];
    #pragma unroll
    for (int off = 32; off > 0; off >>= 1) s += __shfl_down(s, off, 64);
    const int wave = threadIdx.x >> 6;
    if ((threadIdx.x & 63) == 0) ws[wave] = s;
    __syncthreads();
    if (threadIdx.x == 0) {
        float t = 0.f;
        #pragma unroll
        for (int i = 0; i < 16; i++) t += ws[i];
        bsum[blockIdx.x] = t;
    }
}

// Stage-2 reduce: one wave sums the 24 block sums and divides.
__global__ void reduce2_kernel(const float* __restrict__ bsum, float* __restrict__ out)
{
    float s = (threadIdx.x < NRB) ? bsum[threadIdx.x] : 0.f;
    #pragma unroll
    for (int off = 32; off > 0; off >>= 1) s += __shfl_down(s, off, 64);
    if (threadIdx.x == 0) out[0] = s * (1.0f / (float)NVALID);
}

__global__ void finalize_kernel(const float* __restrict__ accum, float* __restrict__ out) {
    out[0] = accum[0] * (1.0f / (float)NVALID);
}

extern "C" void kernel_launch(void* const* d_in, const int* in_sizes, int n_in,
                              void* d_out, int out_size, void* d_ws, size_t ws_size,
                              hipStream_t stream) {
    const float* x = (const float*)d_in[0];
    const float* y = (const float*)d_in[1];
    float* out = (float*)d_out;
    float* ws = (float*)d_ws;

    // Gaussian window, computed in double like the numpy reference, cast to f32.
    Weights wt;
    {
        double g[11], s = 0.0;
        for (int i = 0; i < 11; i++) {
            double d = (double)(i - 5);
            g[i] = exp(-(d * d) / (2.0 * 1.5 * 1.5));
            s += g[i];
        }
        for (int i = 0; i < 11; i++) wt.g[i] = (float)(g[i] / s);
    }

    dim3 grid(NBLKX, NBLKY, 48);
    const size_t need = (size_t)(NPART + NRB) * sizeof(float);
    const int use_atomic = (ws_size < need) ? 1 : 0;
    if (use_atomic) {
        hipMemsetAsync(ws, 0, sizeof(float), stream);
        ssim_kernel<<<grid, 256, 0, stream>>>(x, y, ws, ws, 1, wt);
        finalize_kernel<<<1, 1, 0, stream>>>(ws, out);
    } else {
        float* bsum = ws + NPART;
        ssim_kernel<<<grid, 256, 0, stream>>>(x, y, ws, ws, 0, wt);
        reduce1_kernel<<<NRB, 1024, 0, stream>>>(ws, bsum);
        reduce2_kernel<<<1, 64, 0, stream>>>(bsum, out);
    }
}

// Round 13
// 59.094 us; speedup vs baseline: 11.8135x; 1.3990x over previous
//
#include <hip/hip_runtime.h>
#include <cmath>

// SSIM fused kernel v13 = v12 block structure + column-parallel phase 2.
// - Phase 2: each thread owns 1 col x 8 rows (256 thr = 32 cols x 64 rows),
//   sliding an 18-row window with scalar ds_read_b32: 72 reads = 18 KB/wave
//   (was 48 x b128 = 49 KB). All read addresses = one vaddr + compile-time
//   offsets (plane*9472 + row*128 < 64K) -> near-zero addressing VALU.
//   Banks: 32 lanes read 32 consecutive floats (perfect); 2nd half-wave reads
//   another row = 2-way aliasing = free (m136).
// - Phase 1: natural row order (even/odd interleave no longer needed).
// - Keeps: 4-plane algebra, rcpf, parallel 2-stage tail, no launch_bounds
//   2nd arg (burned twice).

#define W 512
#define H 512
#define OWD 502
#define OHD 502
#define TILEC 32
#define TILER 64
#define INR 74            // halo'd rows
#define NVALID 12096192   // 48 * 502 * 502
#define NBLKX 16
#define NBLKY 8
#define NPART (NBLKX * NBLKY * 48 * 4)   // 24576 = one partial per wave
#define NRB 24                            // reduce1 blocks (24*1024 = NPART)

struct Weights { float g[11]; };

__global__ __launch_bounds__(256) void ssim_kernel(
    const float* __restrict__ x, const float* __restrict__ y,
    float* __restrict__ partial, float* __restrict__ accum, int use_atomic, Weights wt)
{
    __shared__ __align__(16) float hb[4][INR][TILEC];

    const int tid = threadIdx.x;
    const int r0 = blockIdx.y * TILER;
    const int c0 = blockIdx.x * TILEC;
    const size_t plane = (size_t)blockIdx.z * (W * H);
    const float* xp = x + plane;
    const float* yp = y + plane;

    // ---- Phase 1: horizontal pass over 74 rows x 8 col-groups (natural order).
    for (int i = tid; i < INR * 8; i += 256) {
        const int p = i >> 3;                 // row 0..73
        const int cg = (i & 7) << 2;          // col group offset 0..28
        const int gr = r0 + p;
        float xv[16], yv[16];
        if (gr < H) {
            const float* xr = xp + (size_t)gr * W;
            const float* yr = yp + (size_t)gr * W;
            #pragma unroll
            for (int q = 0; q < 4; q++) {
                const int gc = c0 + cg + 4 * q;
                float4 a = make_float4(0.f, 0.f, 0.f, 0.f);
                float4 b = make_float4(0.f, 0.f, 0.f, 0.f);
                if (gc < W) {  // W%4==0, gc%4==0 -> float4 fully in or out
                    a = *(const float4*)(xr + gc);
                    b = *(const float4*)(yr + gc);
                }
                xv[4*q+0] = a.x; xv[4*q+1] = a.y; xv[4*q+2] = a.z; xv[4*q+3] = a.w;
                yv[4*q+0] = b.x; yv[4*q+1] = b.y; yv[4*q+2] = b.z; yv[4*q+3] = b.w;
            }
        } else {
            #pragma unroll
            for (int j = 0; j < 16; j++) { xv[j] = 0.f; yv[j] = 0.f; }
        }
        // Hoisted products: ss = x^2 + y^2 (one plane), xy.
        float ssv[16], xyv[16];
        #pragma unroll
        for (int j = 0; j < 16; j++) {
            ssv[j] = xv[j] * xv[j] + yv[j] * yv[j];
            xyv[j] = xv[j] * yv[j];
        }
        float m1[4]  = {0.f, 0.f, 0.f, 0.f};
        float m2[4]  = {0.f, 0.f, 0.f, 0.f};
        float ms[4]  = {0.f, 0.f, 0.f, 0.f};
        float mx[4]  = {0.f, 0.f, 0.f, 0.f};
        #pragma unroll
        for (int k2 = 0; k2 < 11; k2++) {
            const float w = wt.g[k2];
            #pragma unroll
            for (int j = 0; j < 4; j++) {
                m1[j] += w * xv[j + k2];
                m2[j] += w * yv[j + k2];
                ms[j] += w * ssv[j + k2];
                mx[j] += w * xyv[j + k2];
            }
        }
        *(float4*)&hb[0][p][cg] = make_float4(m1[0], m1[1], m1[2], m1[3]);
        *(float4*)&hb[1][p][cg] = make_float4(m2[0], m2[1], m2[2], m2[3]);
        *(float4*)&hb[2][p][cg] = make_float4(ms[0], ms[1], ms[2], ms[3]);
        *(float4*)&hb[3][p][cg] = make_float4(mx[0], mx[1], mx[2], mx[3]);
    }
    __syncthreads();

    // ---- Phase 2: column-parallel vertical pass + SSIM.
    // Thread = 1 col x 8 output rows; 18-row sliding window, scalar reads.
    float lsum = 0.f;
    {
        const int o8 = (tid >> 5) << 3;   // octet base row: 0,8,...,56
        const int col = tid & 31;

        float am1[8], am2[8], as2[8], ax2[8];
        #pragma unroll
        for (int r = 0; r < 8; r++) {
            am1[r] = 0.f; am2[r] = 0.f; as2[r] = 0.f; ax2[r] = 0.f;
        }

        #pragma unroll
        for (int t = 0; t < 18; t++) {
            const int row = o8 + t;
            const float m1 = hb[0][row][col];
            const float m2 = hb[1][row][col];
            const float ms = hb[2][row][col];
            const float mx = hb[3][row][col];
            #pragma unroll
            for (int r = 0; r < 8; r++) {
                const int k = t - r;
                if (k >= 0 && k <= 10) {
                    const float w = wt.g[k];
                    am1[r] += w * m1;
                    am2[r] += w * m2;
                    as2[r] += w * ms;
                    ax2[r] += w * mx;
                }
            }
        }

        const float C1 = 1e-4f;   // (0.01*1)^2
        const float C2 = 9e-4f;   // (0.03*1)^2
        const int ocol = c0 + col;
        if (ocol < OWD) {
            #pragma unroll
            for (int r = 0; r < 8; r++) {
                const int orow = r0 + o8 + r;
                if (orow < OHD) {
                    const float mu1 = am1[r], mu2 = am2[r];
                    const float mu12 = mu1 * mu2;
                    const float mu1s = mu1 * mu1;
                    const float mu2s = mu2 * mu2;
                    const float sss = as2[r] - mu1s - mu2s;  // s11+s22
                    const float s12 = ax2[r] - mu12;
                    const float num = (2.f * mu12 + C1) * (2.f * s12 + C2);
                    const float den = (mu1s + mu2s + C1) * (sss + C2);
                    lsum += num * __builtin_amdgcn_rcpf(den);
                }
            }
        }
    }

    // ---- Per-wave reduction; one partial (or atomic) per wave.
    #pragma unroll
    for (int off = 32; off > 0; off >>= 1) lsum += __shfl_down(lsum, off, 64);
    if ((tid & 63) == 0) {
        const int wave = tid >> 6;
        const int bid = (blockIdx.z * NBLKY + blockIdx.y) * NBLKX + blockIdx.x;
        if (use_atomic) unsafeAtomicAdd(accum, lsum);
        else partial[bid * 4 + wave] = lsum;
    }
}

// Stage-1 reduce: 24 blocks x 1024 threads, each block sums a 1024-chunk.
__global__ __launch_bounds__(1024) void reduce1_kernel(
    const float* __restrict__ partial, float* __restrict__ bsum)
{
    __shared__ float ws[16];
    float s = partial[blockIdx.x * 1024 + threadIdx.x];
    #pragma unroll
    for (int off = 32; off > 0; off >>= 1) s += __shfl_down(s, off, 64);
    const int wave = threadIdx.x >> 6;
    if ((threadIdx.x & 63) == 0) ws[wave] = s;
    __syncthreads();
    if (threadIdx.x == 0) {
        float t = 0.f;
        #pragma unroll
        for (int i = 0; i < 16; i++) t += ws[i];
        bsum[blockIdx.x] = t;
    }
}

// Stage-2 reduce: one wave sums the 24 block sums and divides.
__global__ void reduce2_kernel(const float* __restrict__ bsum, float* __restrict__ out)
{
    float s = (threadIdx.x < NRB) ? bsum[threadIdx.x] : 0.f;
    #pragma unroll
    for (int off = 32; off > 0; off >>= 1) s += __shfl_down(s, off, 64);
    if (threadIdx.x == 0) out[0] = s * (1.0f / (float)NVALID);
}

__global__ void finalize_kernel(const float* __restrict__ accum, float* __restrict__ out) {
    out[0] = accum[0] * (1.0f / (float)NVALID);
}

extern "C" void kernel_launch(void* const* d_in, const int* in_sizes, int n_in,
                              void* d_out, int out_size, void* d_ws, size_t ws_size,
                              hipStream_t stream) {
    const float* x = (const float*)d_in[0];
    const float* y = (const float*)d_in[1];
    float* out = (float*)d_out;
    float* ws = (float*)d_ws;

    // Gaussian window, computed in double like the numpy reference, cast to f32.
    Weights wt;
    {
        double g[11], s = 0.0;
        for (int i = 0; i < 11; i++) {
            double d = (double)(i - 5);
            g[i] = exp(-(d * d) / (2.0 * 1.5 * 1.5));
            s += g[i];
        }
        for (int i = 0; i < 11; i++) wt.g[i] = (float)(g[i] / s);
    }

    dim3 grid(NBLKX, NBLKY, 48);
    const size_t need = (size_t)(NPART + NRB) * sizeof(float);
    const int use_atomic = (ws_size < need) ? 1 : 0;
    if (use_atomic) {
        hipMemsetAsync(ws, 0, sizeof(float), stream);
        ssim_kernel<<<grid, 256, 0, stream>>>(x, y, ws, ws, 1, wt);
        finalize_kernel<<<1, 1, 0, stream>>>(ws, out);
    } else {
        float* bsum = ws + NPART;
        ssim_kernel<<<grid, 256, 0, stream>>>(x, y, ws, ws, 0, wt);
        reduce1_kernel<<<NRB, 1024, 0, stream>>>(ws, bsum);
        reduce2_kernel<<<1, 64, 0, stream>>>(bsum, out);
    }
}